// Round 1
// baseline (493.166 us; speedup 1.0000x reference)
//
#include <hip/hip_runtime.h>

// WindowAttention: x(128,256,512) -> qkv -> windowed attn (epeg conv over query
// axis + rel-pos bias + softmax) -> proj. Full bf16-MFMA pipeline.
//
// ws layout (bytes):
//   [0)          xbf   33,554,432  (x in bf16; REUSED as attnout after gemm_qkv)
//   [33554432)   w1     1,572,864  (qkv_w bf16)
//   [35127296)   w2       524,288  (proj_w bf16)
//   [35651584)   qb    33,554,432  (q scaled, (b,h,n,d) bf16)
//   [69206016)   kb    33,554,432  ((b,h,m,d) bf16)
//   [102760448)  vtb   33,554,432  (V transposed (b,h,d,m) bf16)
//   total ~136.3 MB

typedef unsigned short u16;
typedef unsigned int u32;
typedef __attribute__((ext_vector_type(8))) short short8;   // 8 bf16 (4 VGPRs)
typedef __attribute__((ext_vector_type(4))) float f32x4;

__device__ __forceinline__ u16 f2bf(float f) {
  union { float f; u32 u; } v; v.f = f;
  return (u16)((v.u + 0x7FFFu + ((v.u >> 16) & 1u)) >> 16);  // RNE
}
__device__ __forceinline__ float bf2f(u16 s) {
  union { u32 u; float f; } v; v.u = ((u32)s) << 16;
  return v.f;
}

// async global->LDS, 16B per lane; LDS dest must be wave-uniform base (+lane*16 implicit)
__device__ __forceinline__ void gl2lds16(const u16* g, u16* l) {
  __builtin_amdgcn_global_load_lds((const __attribute__((address_space(1))) void*)g,
                                   (__attribute__((address_space(3))) void*)l, 16, 0, 0);
}

// ---------------- fp32 -> bf16 conversion (x, qkv_w, proj_w in one launch) ---
__global__ __launch_bounds__(256) void cvt_all(
    const float* __restrict__ x, const float* __restrict__ w1f,
    const float* __restrict__ w2f, u16* __restrict__ xo,
    u16* __restrict__ w1o, u16* __restrict__ w2o) {
  const int NX = 4194304;   // 128*256*512 / 4
  const int NW1 = 196608;   // 1536*512 / 4
  const int NW2 = 65536;    // 512*512 / 4
  int i = blockIdx.x * 256 + threadIdx.x;
  const float* src; u16* dst; int j;
  if (i < NX)             { src = x;   dst = xo;  j = i; }
  else if (i < NX + NW1)  { src = w1f; dst = w1o; j = i - NX; }
  else if (i < NX + NW1 + NW2) { src = w2f; dst = w2o; j = i - NX - NW1; }
  else return;
  float4 f = ((const float4*)src)[j];
  uint2 o;
  o.x = (u32)f2bf(f.x) | ((u32)f2bf(f.y) << 16);
  o.y = (u32)f2bf(f.z) | ((u32)f2bf(f.w) << 16);
  ((uint2*)dst)[j] = o;
}

// ---------------- shared GEMM core: C[128x128] = A[128xK] * B[128xK]^T -------
// 256 thr = 4 waves in 2x2; each wave 64x64 = 4x4 tiles of 16x16x32 bf16 MFMA.
template <int KDIM>
__device__ __forceinline__ void gemm_core(const u16* __restrict__ A,
                                          const u16* __restrict__ B,
                                          int m0, int n0,
                                          u16* As, u16* Bs, f32x4 acc[4][4]) {
  int tid = threadIdx.x, wave = tid >> 6, lane = tid & 63;
  int wm = wave >> 1, wn = wave & 1;
  int lr = lane >> 3, lc = (lane & 7) * 8;
  const u16* Ag = A + (size_t)(m0 + wave * 32 + lr) * KDIM + lc;
  const u16* Bg = B + (size_t)(n0 + wave * 32 + lr) * KDIM + lc;
  u16* AsW = As + wave * 32 * 64;   // wave-uniform LDS base
  u16* BsW = Bs + wave * 32 * 64;
  for (int k0 = 0; k0 < KDIM; k0 += 64) {
#pragma unroll
    for (int it = 0; it < 4; ++it) {
      gl2lds16(Ag + k0 + it * 8 * KDIM, AsW + it * 8 * 64);
      gl2lds16(Bg + k0 + it * 8 * KDIM, BsW + it * 8 * 64);
    }
    __syncthreads();   // drains vmcnt (global_load_lds) + lgkm
    int q8 = (lane >> 4) * 8;
#pragma unroll
    for (int ks = 0; ks < 64; ks += 32) {
      short8 af[4], bf8[4];
#pragma unroll
      for (int t = 0; t < 4; ++t) {
        af[t]  = *(const short8*)(As + (wm * 64 + t * 16 + (lane & 15)) * 64 + ks + q8);
        bf8[t] = *(const short8*)(Bs + (wn * 64 + t * 16 + (lane & 15)) * 64 + ks + q8);
      }
#pragma unroll
      for (int tm = 0; tm < 4; ++tm)
#pragma unroll
        for (int tn = 0; tn < 4; ++tn)
          acc[tm][tn] = __builtin_amdgcn_mfma_f32_16x16x32_bf16(
              af[tm], bf8[tn], acc[tm][tn], 0, 0, 0);
    }
    __syncthreads();
  }
}

// ---------------- GEMM1: qkv = x @ qkv_w^T + b; scatter to q(scaled)/k/vT ----
__global__ __launch_bounds__(256) void gemm_qkv(
    const u16* __restrict__ A, const u16* __restrict__ B,
    const float* __restrict__ qkvb, u16* __restrict__ qb,
    u16* __restrict__ kb, u16* __restrict__ vtb) {
  __shared__ __align__(16) u16 As[128 * 64];
  __shared__ __align__(16) u16 Bs[128 * 64];
  f32x4 acc[4][4];
#pragma unroll
  for (int a = 0; a < 4; ++a)
#pragma unroll
    for (int c = 0; c < 4; ++c) acc[a][c] = (f32x4){0.f, 0.f, 0.f, 0.f};
  int m0 = blockIdx.x * 128, n0 = blockIdx.y * 128;
  gemm_core<512>(A, B, m0, n0, As, Bs, acc);
  int tid = threadIdx.x, wave = tid >> 6, lane = tid & 63;
  int wm = wave >> 1, wn = wave & 1;
#pragma unroll
  for (int tm = 0; tm < 4; ++tm) {
    int rbase = m0 + wm * 64 + tm * 16 + (lane >> 4) * 4;
#pragma unroll
    for (int tn = 0; tn < 4; ++tn) {
      int c = n0 + wn * 64 + tn * 16 + (lane & 15);
      float bv = qkvb[c];
      int which = c >> 9, cc = c & 511;
      int h = cc >> 6, d = cc & 63;
#pragma unroll
      for (int i = 0; i < 4; ++i) {
        int r = rbase + i;
        int b = r >> 8, n = r & 255;
        float v = acc[tm][tn][i] + bv;
        int bh = b * 8 + h;
        if (which == 0)      qb[((size_t)bh * 256 + n) * 64 + d] = f2bf(v * 0.125f);
        else if (which == 1) kb[((size_t)bh * 256 + n) * 64 + d] = f2bf(v);
        else                 vtb[((size_t)bh * 64 + d) * 256 + n] = f2bf(v);
      }
    }
  }
}

// ---------------- attention: 1 wg (512 thr) per (b,h) window ------------------
// LDS: Q 32K + K 32K + Vt 32K + Sb(80x256 bf16) 40K + bias 3.8K = ~143 KB
__global__ __launch_bounds__(512) void attn_win(
    const u16* __restrict__ qb, const u16* __restrict__ kb,
    const u16* __restrict__ vtb, const float* __restrict__ pe_w,
    const float* __restrict__ pe_b, const float* __restrict__ rpb,
    u16* __restrict__ attnout) {
  __shared__ __align__(16) u16 Ql[256 * 64];
  __shared__ __align__(16) u16 Kl[256 * 64];
  __shared__ __align__(16) u16 Vt[64 * 256];
  __shared__ __align__(16) u16 Sb[80 * 256];
  __shared__ float biasl[961];
  __shared__ float pwe2[32];   // zero-padded effective conv weights (identity folded at idx 14)
  __shared__ float pebs;

  int bh = blockIdx.x;
  int b = bh >> 3, h = bh & 7;
  int tid = threadIdx.x, wave = tid >> 6, lane = tid & 63;

  // phase 0: stage Q, K, Vt, bias table, conv weights
  {
    const uint4* qs = (const uint4*)(qb + (size_t)bh * 16384);
    const uint4* ks = (const uint4*)(kb + (size_t)bh * 16384);
    const uint4* vs = (const uint4*)(vtb + (size_t)bh * 16384);
    uint4* qd = (uint4*)Ql; uint4* kd = (uint4*)Kl; uint4* vd = (uint4*)Vt;
#pragma unroll
    for (int it = 0; it < 4; ++it) {
      int idx = tid + it * 512;
      qd[idx] = qs[idx]; kd[idx] = ks[idx]; vd[idx] = vs[idx];
    }
    for (int i = tid; i < 961; i += 512) biasl[i] = rpb[i * 8 + h];
    if (tid < 32) {
      int k = tid - 7;
      float v = 0.f;
      if (k >= 0 && k <= 14) { v = pe_w[h * 15 + k]; if (k == 7) v += 1.f; }
      pwe2[tid] = v;
    }
    if (tid == 32) pebs = pe_b[h];
  }
  __syncthreads();

  for (int nb = 0; nb < 256; nb += 64) {
    int rows_lo = (nb == 0) ? 0 : nb - 7;
    int q8 = (lane >> 4) * 8;

    // phase 1: S_raw rows [rows_lo .. rows_lo+79] x m[0..255] -> Sb (bf16)
    for (int t = wave; t < 80; t += 8) {
      int nt = t >> 4, mt = t & 15;
      int qrow = rows_lo + nt * 16 + (lane & 15);
      if (qrow > 255) qrow = 255;                  // halo overrun: garbage, never read
      int krow = mt * 16 + (lane & 15);
      f32x4 acc = (f32x4){0.f, 0.f, 0.f, 0.f};
#pragma unroll
      for (int ks2 = 0; ks2 < 64; ks2 += 32) {
        short8 a  = *(const short8*)(Ql + qrow * 64 + ks2 + q8);
        short8 bb = *(const short8*)(Kl + krow * 64 + ks2 + q8);
        acc = __builtin_amdgcn_mfma_f32_16x16x32_bf16(a, bb, acc, 0, 0, 0);
      }
      int m = mt * 16 + (lane & 15);
      int rrow = nt * 16 + (lane >> 4) * 4;
#pragma unroll
      for (int i = 0; i < 4; ++i) Sb[(rrow + i) * 256 + m] = f2bf(acc[i]);
    }
    __syncthreads();

    // phase 2a: conv(over n) + identity + pe_b + rel-pos bias into registers.
    // wave owns rows n0w..n0w+7; lane owns m = lane*4..lane*4+3 (one b64 read/row).
    float av[8][4];
#pragma unroll
    for (int rr = 0; rr < 8; ++rr)
#pragma unroll
      for (int j = 0; j < 4; ++j) av[rr][j] = 0.f;
    int n0w = nb + wave * 8;
    int ir_lo = n0w - 7;  if (ir_lo < 0)   ir_lo = 0;
    int ir_hi = n0w + 14; if (ir_hi > 255) ir_hi = 255;
    for (int ir = ir_lo; ir <= ir_hi; ++ir) {
      uint2 rv = *(const uint2*)(Sb + (ir - rows_lo) * 256 + lane * 4);
      float f0 = bf2f(rv.x & 0xffff), f1 = bf2f(rv.x >> 16);
      float f2v = bf2f(rv.y & 0xffff), f3 = bf2f(rv.y >> 16);
      int bidx = ir - n0w + 14;   // in [7,28]; bidx-rr in [0,28]
#pragma unroll
      for (int rr = 0; rr < 8; ++rr) {
        float w = pwe2[bidx - rr];   // uniform LDS broadcast
        av[rr][0] += w * f0; av[rr][1] += w * f1;
        av[rr][2] += w * f2v; av[rr][3] += w * f3;
      }
    }
#pragma unroll
    for (int rr = 0; rr < 8; ++rr) {
      int n = n0w + rr;
      int dyb = ((n >> 4) - (lane >> 2) + 15) * 31;
#pragma unroll
      for (int j = 0; j < 4; ++j) {
        int dx = (n & 15) - ((lane & 3) * 4 + j) + 15;
        av[rr][j] += pebs + biasl[dyb + dx];
      }
    }
    __syncthreads();   // all conv inputs consumed before P overwrites Sb

    // phase 2b: softmax per row (wave-owned; shfl reductions), write P in place
#pragma unroll
    for (int rr = 0; rr < 8; ++rr) {
      int n = n0w + rr;
      float mx = fmaxf(fmaxf(av[rr][0], av[rr][1]), fmaxf(av[rr][2], av[rr][3]));
#pragma unroll
      for (int off = 32; off > 0; off >>= 1) mx = fmaxf(mx, __shfl_xor(mx, off));
      float e0 = __expf(av[rr][0] - mx), e1 = __expf(av[rr][1] - mx);
      float e2 = __expf(av[rr][2] - mx), e3 = __expf(av[rr][3] - mx);
      float s = e0 + e1 + e2 + e3;
#pragma unroll
      for (int off = 32; off > 0; off >>= 1) s += __shfl_xor(s, off);
      float inv = 1.f / s;
      uint2 pv;
      pv.x = (u32)f2bf(e0 * inv) | ((u32)f2bf(e1 * inv) << 16);
      pv.y = (u32)f2bf(e2 * inv) | ((u32)f2bf(e3 * inv) << 16);
      *(uint2*)(Sb + (n - rows_lo) * 256 + lane * 4) = pv;
    }
    __syncthreads();

    // phase 3: O[64x64] = P[64x256] @ V[256x64]; 16 tiles over 8 waves
    int prow_off = nb - rows_lo;   // 0 or 7
#pragma unroll
    for (int tt2 = 0; tt2 < 2; ++tt2) {
      int tt = wave * 2 + tt2;
      int nt = tt >> 2, dt = tt & 3;
      f32x4 acc = (f32x4){0.f, 0.f, 0.f, 0.f};
#pragma unroll
      for (int km = 0; km < 8; ++km) {
        short8 a  = *(const short8*)(Sb + (prow_off + nt * 16 + (lane & 15)) * 256 + km * 32 + q8);
        short8 bb = *(const short8*)(Vt + (dt * 16 + (lane & 15)) * 256 + km * 32 + q8);
        acc = __builtin_amdgcn_mfma_f32_16x16x32_bf16(a, bb, acc, 0, 0, 0);
      }
      int n = nb + nt * 16 + (lane >> 4) * 4;
      int d = dt * 16 + (lane & 15);
#pragma unroll
      for (int i = 0; i < 4; ++i)
        attnout[((size_t)b * 256 + n + i) * 512 + h * 64 + d] = f2bf(acc[i]);
    }
    __syncthreads();   // Sb reused by next block's phase 1
  }
}

// ---------------- GEMM2: out = attnout @ proj_w^T + proj_b (fp32 out) --------
__global__ __launch_bounds__(256) void gemm_proj(
    const u16* __restrict__ A, const u16* __restrict__ B,
    const float* __restrict__ pb, float* __restrict__ out) {
  __shared__ __align__(16) u16 As[128 * 64];
  __shared__ __align__(16) u16 Bs[128 * 64];
  f32x4 acc[4][4];
#pragma unroll
  for (int a = 0; a < 4; ++a)
#pragma unroll
    for (int c = 0; c < 4; ++c) acc[a][c] = (f32x4){0.f, 0.f, 0.f, 0.f};
  int m0 = blockIdx.x * 128, n0 = blockIdx.y * 128;
  gemm_core<512>(A, B, m0, n0, As, Bs, acc);
  int tid = threadIdx.x, wave = tid >> 6, lane = tid & 63;
  int wm = wave >> 1, wn = wave & 1;
#pragma unroll
  for (int tm = 0; tm < 4; ++tm) {
    int rbase = m0 + wm * 64 + tm * 16 + (lane >> 4) * 4;
#pragma unroll
    for (int tn = 0; tn < 4; ++tn) {
      int c = n0 + wn * 64 + tn * 16 + (lane & 15);
      float bv = pb[c];
#pragma unroll
      for (int i = 0; i < 4; ++i)
        out[(size_t)(rbase + i) * 512 + c] = acc[tm][tn][i] + bv;
    }
  }
}

extern "C" void kernel_launch(void* const* d_in, const int* in_sizes, int n_in,
                              void* d_out, int out_size, void* d_ws, size_t ws_size,
                              hipStream_t stream) {
  const float* x      = (const float*)d_in[0];
  const float* qkv_w  = (const float*)d_in[1];
  const float* qkv_b  = (const float*)d_in[2];
  const float* pe_w   = (const float*)d_in[3];
  const float* pe_b   = (const float*)d_in[4];
  const float* rpb    = (const float*)d_in[5];
  const float* proj_w = (const float*)d_in[6];
  const float* proj_b = (const float*)d_in[7];
  float* out = (float*)d_out;
  char* ws = (char*)d_ws;

  size_t off = 0;
  u16* xbf = (u16*)(ws + off); off += (size_t)16777216 * 2;  // also attnout
  u16* w1  = (u16*)(ws + off); off += (size_t)786432 * 2;
  u16* w2  = (u16*)(ws + off); off += (size_t)262144 * 2;
  u16* qb  = (u16*)(ws + off); off += (size_t)16777216 * 2;
  u16* kb  = (u16*)(ws + off); off += (size_t)16777216 * 2;
  u16* vtb = (u16*)(ws + off); off += (size_t)16777216 * 2;

  hipLaunchKernelGGL(cvt_all, dim3(17408), dim3(256), 0, stream,
                     x, qkv_w, proj_w, xbf, w1, w2);
  hipLaunchKernelGGL(gemm_qkv, dim3(256, 12), dim3(256), 0, stream,
                     xbf, w1, qkv_b, qb, kb, vtb);
  hipLaunchKernelGGL(attn_win, dim3(1024), dim3(512), 0, stream,
                     qb, kb, vtb, pe_w, pe_b, rpb, xbf);
  hipLaunchKernelGGL(gemm_proj, dim3(256, 4), dim3(256), 0, stream,
                     xbf, w2, proj_b, out);
}

// Round 2
// 395.293 us; speedup vs baseline: 1.2476x; 1.2476x over previous
//
#include <hip/hip_runtime.h>

// WindowAttention: x(128,256,512) -> qkv -> windowed attn (epeg conv folded
// into Q: conv_n(Q K^T) == (conv_n Q) K^T) -> proj. Full bf16-MFMA pipeline.
//
// ws layout (bytes):
//   [0)          xbf   33,554,432  (x in bf16; REUSED as attnout after gemm_qkv)
//   [33554432)   w1     1,572,864  (qkv_w bf16)
//   [35127296)   w2       524,288  (proj_w bf16)
//   [35651584)   qb    33,554,432  (q scaled, (b,h,n,d) bf16; conv'd in place)
//   [69206016)   kb    33,554,432  ((b,h,m,d) bf16)
//   [102760448)  vb    33,554,432  (V row-major (b,h,n,d) bf16)

typedef unsigned short u16;
typedef unsigned int u32;
typedef __attribute__((ext_vector_type(8))) short short8;   // 8 bf16 (4 VGPRs)
typedef __attribute__((ext_vector_type(4))) float f32x4;

__device__ __forceinline__ u16 f2bf(float f) {
  union { float f; u32 u; } v; v.f = f;
  return (u16)((v.u + 0x7FFFu + ((v.u >> 16) & 1u)) >> 16);  // RNE
}
__device__ __forceinline__ float bf2f(u16 s) {
  union { u32 u; float f; } v; v.u = ((u32)s) << 16;
  return v.f;
}

__device__ __forceinline__ void gl2lds16(const u16* g, u16* l) {
  __builtin_amdgcn_global_load_lds((const __attribute__((address_space(1))) void*)g,
                                   (__attribute__((address_space(3))) void*)l, 16, 0, 0);
}

// ---------------- fp32 -> bf16 conversion (x, qkv_w, proj_w) -----------------
__global__ __launch_bounds__(256) void cvt_all(
    const float* __restrict__ x, const float* __restrict__ w1f,
    const float* __restrict__ w2f, u16* __restrict__ xo,
    u16* __restrict__ w1o, u16* __restrict__ w2o) {
  const int NX = 4194304, NW1 = 196608, NW2 = 65536;
  int i = blockIdx.x * 256 + threadIdx.x;
  const float* src; u16* dst; int j;
  if (i < NX)                  { src = x;   dst = xo;  j = i; }
  else if (i < NX + NW1)       { src = w1f; dst = w1o; j = i - NX; }
  else if (i < NX + NW1 + NW2) { src = w2f; dst = w2o; j = i - NX - NW1; }
  else return;
  float4 f = ((const float4*)src)[j];
  uint2 o;
  o.x = (u32)f2bf(f.x) | ((u32)f2bf(f.y) << 16);
  o.y = (u32)f2bf(f.z) | ((u32)f2bf(f.w) << 16);
  ((uint2*)dst)[j] = o;
}

// ---------------- shared GEMM core: C[128x128] = A[128xK] * B[128xK]^T -------
template <int KDIM>
__device__ __forceinline__ void gemm_core(const u16* __restrict__ A,
                                          const u16* __restrict__ B,
                                          int m0, int n0,
                                          u16* As, u16* Bs, f32x4 acc[4][4]) {
  int tid = threadIdx.x, wave = tid >> 6, lane = tid & 63;
  int wm = wave >> 1, wn = wave & 1;
  int lr = lane >> 3, lc = (lane & 7) * 8;
  const u16* Ag = A + (size_t)(m0 + wave * 32 + lr) * KDIM + lc;
  const u16* Bg = B + (size_t)(n0 + wave * 32 + lr) * KDIM + lc;
  u16* AsW = As + wave * 32 * 64;
  u16* BsW = Bs + wave * 32 * 64;
  for (int k0 = 0; k0 < KDIM; k0 += 64) {
#pragma unroll
    for (int it = 0; it < 4; ++it) {
      gl2lds16(Ag + k0 + it * 8 * KDIM, AsW + it * 8 * 64);
      gl2lds16(Bg + k0 + it * 8 * KDIM, BsW + it * 8 * 64);
    }
    __syncthreads();
    int q8 = (lane >> 4) * 8;
#pragma unroll
    for (int ks = 0; ks < 64; ks += 32) {
      short8 af[4], bf8[4];
#pragma unroll
      for (int t = 0; t < 4; ++t) {
        af[t]  = *(const short8*)(As + (wm * 64 + t * 16 + (lane & 15)) * 64 + ks + q8);
        bf8[t] = *(const short8*)(Bs + (wn * 64 + t * 16 + (lane & 15)) * 64 + ks + q8);
      }
#pragma unroll
      for (int tm = 0; tm < 4; ++tm)
#pragma unroll
        for (int tn = 0; tn < 4; ++tn)
          acc[tm][tn] = __builtin_amdgcn_mfma_f32_16x16x32_bf16(
              af[tm], bf8[tn], acc[tm][tn], 0, 0, 0);
    }
    __syncthreads();
  }
}

// ---------------- GEMM1: qkv = x @ qkv_w^T + b; scatter q(scaled)/k/v --------
__global__ __launch_bounds__(256) void gemm_qkv(
    const u16* __restrict__ A, const u16* __restrict__ B,
    const float* __restrict__ qkvb, u16* __restrict__ qb,
    u16* __restrict__ kb, u16* __restrict__ vb) {
  __shared__ __align__(16) u16 As[128 * 64];
  __shared__ __align__(16) u16 Bs[128 * 64];
  f32x4 acc[4][4];
#pragma unroll
  for (int a = 0; a < 4; ++a)
#pragma unroll
    for (int c = 0; c < 4; ++c) acc[a][c] = (f32x4){0.f, 0.f, 0.f, 0.f};
  int m0 = blockIdx.x * 128, n0 = blockIdx.y * 128;
  gemm_core<512>(A, B, m0, n0, As, Bs, acc);
  int tid = threadIdx.x, wave = tid >> 6, lane = tid & 63;
  int wm = wave >> 1, wn = wave & 1;
#pragma unroll
  for (int tm = 0; tm < 4; ++tm) {
    int rbase = m0 + wm * 64 + tm * 16 + (lane >> 4) * 4;
#pragma unroll
    for (int tn = 0; tn < 4; ++tn) {
      int c = n0 + wn * 64 + tn * 16 + (lane & 15);
      float bv = qkvb[c];
      int which = c >> 9, cc = c & 511;
      int h = cc >> 6, d = cc & 63;
#pragma unroll
      for (int i = 0; i < 4; ++i) {
        int r = rbase + i;
        int b = r >> 8, n = r & 255;
        float v = acc[tm][tn][i] + bv;
        size_t idx = ((size_t)(b * 8 + h) * 256 + n) * 64 + d;
        if (which == 0)      qb[idx] = f2bf(v * 0.125f);
        else if (which == 1) kb[idx] = f2bf(v);
        else                 vb[idx] = f2bf(v);
      }
    }
  }
}

// ---------------- qconv: Q' = Q + conv15_n(Q), in place per (b,h) window -----
__global__ __launch_bounds__(256) void qconv(u16* __restrict__ qb,
                                             const float* __restrict__ pe_w) {
  __shared__ __align__(16) u16 Ql[256 * 72];   // padded stride
  __shared__ float w[15];
  int bh = blockIdx.x, h = bh & 7;
  int tid = threadIdx.x;
  const uint4* src = (const uint4*)(qb + (size_t)bh * 16384);
#pragma unroll
  for (int it = 0; it < 8; ++it) {
    int idx = tid + it * 256;
    int row = idx >> 3, c = (idx & 7) * 8;
    *(uint4*)(Ql + row * 72 + c) = src[idx];
  }
  if (tid < 15) w[tid] = pe_w[h * 15 + tid] + (tid == 7 ? 1.f : 0.f);  // identity folded
  __syncthreads();
  int dg = (tid & 15) * 4, nb4 = tid >> 4;
  uint2* dst = (uint2*)(qb + (size_t)bh * 16384);
#pragma unroll
  for (int i = 0; i < 16; ++i) {
    int n = nb4 + i * 16;
    float a0 = 0.f, a1 = 0.f, a2 = 0.f, a3 = 0.f;
#pragma unroll
    for (int t = 0; t < 15; ++t) {
      int nn = n + t - 7;
      if (nn < 0 || nn > 255) continue;
      uint2 rv = *(const uint2*)(Ql + nn * 72 + dg);
      float wt = w[t];
      a0 += wt * bf2f(rv.x & 0xffff); a1 += wt * bf2f(rv.x >> 16);
      a2 += wt * bf2f(rv.y & 0xffff); a3 += wt * bf2f(rv.y >> 16);
    }
    uint2 pv;
    pv.x = (u32)f2bf(a0) | ((u32)f2bf(a1) << 16);
    pv.y = (u32)f2bf(a2) | ((u32)f2bf(a3) << 16);
    dst[(n * 64 + dg) >> 2] = pv;
  }
}

// ---------------- attention: 1 wg (512 thr) per (b,h) window -----------------
// LDS (padded, conflict-free fragment reads): Ql 36.9K + Kl 36.9K + Vt 33.8K +
// SbU 36.9K (union Vtmp/scores) + bias 3.8K = ~148 KB
__global__ __launch_bounds__(512) void attn_win(
    const u16* __restrict__ qb, const u16* __restrict__ kb,
    const u16* __restrict__ vb, const float* __restrict__ pe_b,
    const float* __restrict__ rpb, u16* __restrict__ attnout) {
  __shared__ __align__(16) u16 Ql[256 * 72];
  __shared__ __align__(16) u16 Kl[256 * 72];
  __shared__ __align__(16) u16 Vt[64 * 264];
  __shared__ __align__(16) u16 SbU[256 * 72];   // Vtmp (256x72) then Sb (64x264)
  __shared__ float biasl[961];
  __shared__ float pebs;

  int bh = blockIdx.x, b = bh >> 3, h = bh & 7;
  int tid = threadIdx.x, wave = tid >> 6, lane = tid & 63;

  // phase 0a: stage Q', K, V(row-major temp), bias
  {
    const uint4* qs = (const uint4*)(qb + (size_t)bh * 16384);
    const uint4* ks = (const uint4*)(kb + (size_t)bh * 16384);
    const uint4* vs = (const uint4*)(vb + (size_t)bh * 16384);
#pragma unroll
    for (int it = 0; it < 4; ++it) {
      int idx = tid + it * 512;
      int row = idx >> 3, c = (idx & 7) * 8;
      *(uint4*)(Ql  + row * 72 + c) = qs[idx];
      *(uint4*)(Kl  + row * 72 + c) = ks[idx];
      *(uint4*)(SbU + row * 72 + c) = vs[idx];
    }
    for (int i = tid; i < 961; i += 512) biasl[i] = rpb[i * 8 + h];
    if (tid == 0) pebs = pe_b[h];
  }
  __syncthreads();

  // phase 0b: transpose V: SbU(n,d stride 72) -> Vt(d,n stride 264)
  {
    int d = tid & 63, ng = tid >> 6;
#pragma unroll
    for (int j = 0; j < 8; ++j) {
      int n0 = ng * 32 + j * 4;
      u16 v0 = SbU[(n0 + 0) * 72 + d];
      u16 v1 = SbU[(n0 + 1) * 72 + d];
      u16 v2 = SbU[(n0 + 2) * 72 + d];
      u16 v3 = SbU[(n0 + 3) * 72 + d];
      uint2 pv;
      pv.x = (u32)v0 | ((u32)v1 << 16);
      pv.y = (u32)v2 | ((u32)v3 << 16);
      *(uint2*)(Vt + d * 264 + n0) = pv;
    }
  }
  __syncthreads();

  u16* Sb = SbU;   // 64 x 264 from here on
  int q8 = (lane >> 4) * 8;

  for (int nb = 0; nb < 256; nb += 64) {
    // phase 1: S[64x256] = Q'[nb..nb+63] K^T  (4x16 tiles, 8 per wave)
#pragma unroll
    for (int tt = 0; tt < 8; ++tt) {
      int t = wave * 8 + tt, nt = t >> 4, mt = t & 15;
      int qrow = nb + nt * 16 + (lane & 15);
      int krow = mt * 16 + (lane & 15);
      f32x4 acc = (f32x4){0.f, 0.f, 0.f, 0.f};
#pragma unroll
      for (int ks2 = 0; ks2 < 64; ks2 += 32) {
        short8 a  = *(const short8*)(Ql + qrow * 72 + ks2 + q8);
        short8 bb = *(const short8*)(Kl + krow * 72 + ks2 + q8);
        acc = __builtin_amdgcn_mfma_f32_16x16x32_bf16(a, bb, acc, 0, 0, 0);
      }
      int m = mt * 16 + (lane & 15);
      int rbase = nt * 16 + (lane >> 4) * 4;
#pragma unroll
      for (int i = 0; i < 4; ++i) Sb[(rbase + i) * 264 + m] = f2bf(acc[i]);
    }
    __syncthreads();

    // phase 2: bias + softmax; wave owns rows wave*8..wave*8+7, lane owns 4 m
#pragma unroll
    for (int rr = 0; rr < 8; ++rr) {
      int r = wave * 8 + rr, n = nb + r;
      uint2 rv = *(const uint2*)(Sb + r * 264 + lane * 4);
      float a0 = bf2f(rv.x & 0xffff), a1 = bf2f(rv.x >> 16);
      float a2 = bf2f(rv.y & 0xffff), a3 = bf2f(rv.y >> 16);
      int dyb = ((n >> 4) - (lane >> 2) + 15) * 31;
      int dxb = (n & 15) - (lane & 3) * 4 + 15;
      a0 += pebs + biasl[dyb + dxb];
      a1 += pebs + biasl[dyb + dxb - 1];
      a2 += pebs + biasl[dyb + dxb - 2];
      a3 += pebs + biasl[dyb + dxb - 3];
      float mx = fmaxf(fmaxf(a0, a1), fmaxf(a2, a3));
#pragma unroll
      for (int off = 32; off > 0; off >>= 1) mx = fmaxf(mx, __shfl_xor(mx, off));
      float e0 = __expf(a0 - mx), e1 = __expf(a1 - mx);
      float e2 = __expf(a2 - mx), e3 = __expf(a3 - mx);
      float s = e0 + e1 + e2 + e3;
#pragma unroll
      for (int off = 32; off > 0; off >>= 1) s += __shfl_xor(s, off);
      float inv = 1.f / s;
      uint2 pv;
      pv.x = (u32)f2bf(e0 * inv) | ((u32)f2bf(e1 * inv) << 16);
      pv.y = (u32)f2bf(e2 * inv) | ((u32)f2bf(e3 * inv) << 16);
      *(uint2*)(Sb + r * 264 + lane * 4) = pv;
    }
    __syncthreads();

    // phase 3: O[64x64] = P[64x256] @ V[256x64]; 16 tiles, 2 per wave
#pragma unroll
    for (int tt2 = 0; tt2 < 2; ++tt2) {
      int tt = wave * 2 + tt2, nt = tt >> 2, dt = tt & 3;
      f32x4 acc = (f32x4){0.f, 0.f, 0.f, 0.f};
#pragma unroll
      for (int km = 0; km < 8; ++km) {
        short8 a  = *(const short8*)(Sb + (nt * 16 + (lane & 15)) * 264 + km * 32 + q8);
        short8 bb = *(const short8*)(Vt + (dt * 16 + (lane & 15)) * 264 + km * 32 + q8);
        acc = __builtin_amdgcn_mfma_f32_16x16x32_bf16(a, bb, acc, 0, 0, 0);
      }
      int n = nb + nt * 16 + (lane >> 4) * 4;
      int d = dt * 16 + (lane & 15);
#pragma unroll
      for (int i = 0; i < 4; ++i)
        attnout[((size_t)b * 256 + n + i) * 512 + h * 64 + d] = f2bf(acc[i]);
    }
    __syncthreads();   // Sb reused by next block's phase 1
  }
}

// ---------------- GEMM2: out = attnout @ proj_w^T + proj_b (fp32 out) --------
__global__ __launch_bounds__(256) void gemm_proj(
    const u16* __restrict__ A, const u16* __restrict__ B,
    const float* __restrict__ pb, float* __restrict__ out) {
  __shared__ __align__(16) u16 As[128 * 64];
  __shared__ __align__(16) u16 Bs[128 * 64];
  f32x4 acc[4][4];
#pragma unroll
  for (int a = 0; a < 4; ++a)
#pragma unroll
    for (int c = 0; c < 4; ++c) acc[a][c] = (f32x4){0.f, 0.f, 0.f, 0.f};
  int m0 = blockIdx.x * 128, n0 = blockIdx.y * 128;
  gemm_core<512>(A, B, m0, n0, As, Bs, acc);
  int tid = threadIdx.x, wave = tid >> 6, lane = tid & 63;
  int wm = wave >> 1, wn = wave & 1;
#pragma unroll
  for (int tm = 0; tm < 4; ++tm) {
    int rbase = m0 + wm * 64 + tm * 16 + (lane >> 4) * 4;
#pragma unroll
    for (int tn = 0; tn < 4; ++tn) {
      int c = n0 + wn * 64 + tn * 16 + (lane & 15);
      float bv = pb[c];
#pragma unroll
      for (int i = 0; i < 4; ++i)
        out[(size_t)(rbase + i) * 512 + c] = acc[tm][tn][i] + bv;
    }
  }
}

extern "C" void kernel_launch(void* const* d_in, const int* in_sizes, int n_in,
                              void* d_out, int out_size, void* d_ws, size_t ws_size,
                              hipStream_t stream) {
  const float* x      = (const float*)d_in[0];
  const float* qkv_w  = (const float*)d_in[1];
  const float* qkv_b  = (const float*)d_in[2];
  const float* pe_w   = (const float*)d_in[3];
  const float* pe_b   = (const float*)d_in[4];
  const float* rpb    = (const float*)d_in[5];
  const float* proj_w = (const float*)d_in[6];
  const float* proj_b = (const float*)d_in[7];
  float* out = (float*)d_out;
  char* ws = (char*)d_ws;

  size_t off = 0;
  u16* xbf = (u16*)(ws + off); off += (size_t)16777216 * 2;  // also attnout
  u16* w1  = (u16*)(ws + off); off += (size_t)786432 * 2;
  u16* w2  = (u16*)(ws + off); off += (size_t)262144 * 2;
  u16* qb  = (u16*)(ws + off); off += (size_t)16777216 * 2;
  u16* kb  = (u16*)(ws + off); off += (size_t)16777216 * 2;
  u16* vb  = (u16*)(ws + off); off += (size_t)16777216 * 2;

  hipLaunchKernelGGL(cvt_all, dim3(17408), dim3(256), 0, stream,
                     x, qkv_w, proj_w, xbf, w1, w2);
  hipLaunchKernelGGL(gemm_qkv, dim3(256, 12), dim3(256), 0, stream,
                     xbf, w1, qkv_b, qb, kb, vb);
  hipLaunchKernelGGL(qconv, dim3(1024), dim3(256), 0, stream, qb, pe_w);
  hipLaunchKernelGGL(attn_win, dim3(1024), dim3(512), 0, stream,
                     qb, kb, vb, pe_b, rpb, xbf);
  hipLaunchKernelGGL(gemm_proj, dim3(256, 4), dim3(256), 0, stream,
                     xbf, w2, proj_b, out);
}